// Round 6
// baseline (406.894 us; speedup 1.0000x reference)
//
#include <hip/hip_runtime.h>

// HVAE loss, fused. Output = scalar f32.
// ws layout: one double partial per block of k_main (no zeroing needed — every
// slot is written before k_final reads it, so the 0xAA poison is harmless).

static constexpr double D_LOG2PI = 1.8378770664093453;   // ln(2*pi)
static constexpr float  KL_C0    = -1.1931471805599453f; // -0.5 + 0.5*ln(0.25)

// softplus(x) = max(x,0) + ln2 * log2(1 + 2^(-|x|*log2e))
// v_exp_f32 / v_log_f32 are base-2 native on gfx950; abs err <~1e-7.
__device__ __forceinline__ float softplus_fast(float x) {
  const float t = __builtin_amdgcn_exp2f(-1.442695041f * fabsf(x));
  return fmaxf(x, 0.f) + 0.6931471806f * __builtin_amdgcn_logf(1.f + t);
}

__device__ __forceinline__ float sp4(const float4 v) {
  return softplus_fast(v.x) + softplus_fast(v.y)
       + softplus_fast(v.z) + softplus_fast(v.w);
}

// Reduce across the block, store ONE double to this block's unique slot.
__device__ __forceinline__ void block_reduce_store(double v, double* slot) {
#pragma unroll
  for (int off = 32; off > 0; off >>= 1)
    v += __shfl_down(v, off, 64);
  __shared__ double s[4];
  const int lane = threadIdx.x & 63;
  const int wv   = threadIdx.x >> 6;
  if (lane == 0) s[wv] = v;
  __syncthreads();
  if (threadIdx.x == 0) *slot = s[0] + s[1] + s[2] + s[3];
}

// One fused kernel, block-range partitioned (wave-uniform branch):
//   blocks [0, spB)            : softplus sum over N^2 logits (8x-unrolled MLP)
//   blocks [spB, spB+edB)      : per-edge symmetric gather sum (1 edge/thread)
//   blocks [spB+edB, grid)     : KL sum over (N,D) latents
__global__ __launch_bounds__(256) void k_main(
    const float4* __restrict__ x4, long long n4,
    const int* __restrict__ eidx, const float* __restrict__ x, int N, int E,
    const float4* __restrict__ zmu_n, const float4* __restrict__ zlv_n,
    const float4* __restrict__ zmu_e, const float4* __restrict__ zlv_e,
    const float4* __restrict__ muA, const float4* __restrict__ muB,
    long long nd4, int d4mask,
    double* __restrict__ partials, int spB, int edB) {
  const int b = blockIdx.x;
  if (b < spB) {
    // ---- softplus scan, 8 independent loads in flight ----
    const long long S = (long long)spB * blockDim.x;
    long long i = (long long)b * blockDim.x + threadIdx.x;
    double local = 0.0;
    for (; i + 7 * S < n4; i += 8 * S) {
      const float4 v0 = x4[i];
      const float4 v1 = x4[i + S];
      const float4 v2 = x4[i + 2 * S];
      const float4 v3 = x4[i + 3 * S];
      const float4 v4 = x4[i + 4 * S];
      const float4 v5 = x4[i + 5 * S];
      const float4 v6 = x4[i + 6 * S];
      const float4 v7 = x4[i + 7 * S];
      const float s = (sp4(v0) + sp4(v1)) + (sp4(v2) + sp4(v3))
                    + (sp4(v4) + sp4(v5)) + (sp4(v6) + sp4(v7));
      local += (double)s;
    }
    for (; i < n4; i += S) local += (double)sp4(x4[i]);
    block_reduce_store(local, partials + b);
  } else if (b < spB + edB) {
    // ---- edge gather: x[i,j] + (i!=j ? x[j,i] : 0) ----
    // Per-wave int64-vs-int32 layout detection: int64 little-endian with
    // values < 2^31 has every odd 32-bit word == 0.
    const int w0 = eidx[2 * (threadIdx.x & 63) + 1];
    const int is64 = (__ballot(w0 == 0) == 0xFFFFFFFFFFFFFFFFull) ? 1 : 0;
    const long long t0 = (long long)(b - spB) * blockDim.x + threadIdx.x;
    const long long stride = (long long)edB * blockDim.x;
    double local = 0.0;
    for (long long e = t0; e < E; e += stride) {
      int i, j;
      if (is64) {
        i = eidx[2 * e];
        j = eidx[2 * ((long long)E + e)];
      } else {
        i = eidx[e];
        j = eidx[(long long)E + e];
      }
      float v = x[(long long)i * N + j];
      if (i != j) v += x[(long long)j * N + i];
      local += (double)v;
    }
    block_reduce_store(local, partials + b);
  } else {
    // ---- KL over latents: f(mu,lv,q) = KL_C0 - 0.5*lv + 2*((mu-q)^2 + exp(lv)) ----
    long long i = (long long)(b - spB - edB) * blockDim.x + threadIdx.x;
    const long long stride = (long long)(gridDim.x - spB - edB) * blockDim.x;
    double local = 0.0;
    for (; i < nd4; i += stride) {
      const int dv = (int)(i & d4mask);
      const float4 qa = muA[dv];
      const float4 qb = muB[dv];
      const float4 me = zmu_e[i];
      const float4 le = zlv_e[i];
      const float4 mn = zmu_n[i];
      const float4 ln_ = zlv_n[i];
      float s = 0.f;
      {
        float d0 = me.x - qa.x, d1 = me.y - qa.y, d2 = me.z - qa.z, d3 = me.w - qa.w;
        s += KL_C0 - 0.5f * le.x + 2.f * (d0 * d0 + __expf(le.x));
        s += KL_C0 - 0.5f * le.y + 2.f * (d1 * d1 + __expf(le.y));
        s += KL_C0 - 0.5f * le.z + 2.f * (d2 * d2 + __expf(le.z));
        s += KL_C0 - 0.5f * le.w + 2.f * (d3 * d3 + __expf(le.w));
      }
      {
        float d0 = mn.x - qb.x, d1 = mn.y - qb.y, d2 = mn.z - qb.z, d3 = mn.w - qb.w;
        s += KL_C0 - 0.5f * ln_.x + 2.f * (d0 * d0 + __expf(ln_.x));
        s += KL_C0 - 0.5f * ln_.y + 2.f * (d1 * d1 + __expf(ln_.y));
        s += KL_C0 - 0.5f * ln_.z + 2.f * (d2 * d2 + __expf(ln_.z));
        s += KL_C0 - 0.5f * ln_.w + 2.f * (d3 * d3 + __expf(ln_.w));
      }
      local += (double)s;
    }
    block_reduce_store(local, partials + b);
  }
}

// Weighted reduction of all block partials + tiny D=64 scalar terms.
__global__ __launch_bounds__(1024) void k_final(
    const double* __restrict__ partials, int nB, int spB, int edB,
    const float* __restrict__ Alpha_mu, const float* __restrict__ Beta_mu,
    const float* __restrict__ mu_A, const float* __restrict__ mu_B,
    float* __restrict__ out, int D, double invN2, double invND) {
  const int tid = threadIdx.x;
  double local = 0.0;
  for (int b = tid; b < nB; b += 1024) {
    const double w = (b < spB) ? invN2 : ((b < spB + edB) ? -invN2 : invND);
    local += partials[b] * w;
  }
  if (tid < D) {
    const double ma = mu_A[tid], mb = mu_B[tid];
    const double aa = Alpha_mu[tid], bb = Beta_mu[tid];
    const double t = -0.5 * (D_LOG2PI + ma * ma) + 2.0 * (ma - aa) * (ma - aa)
                   + -0.5 * (D_LOG2PI + mb * mb) + 2.0 * (mb - bb) * (mb - bb);
    local += t / (double)D;
  }
#pragma unroll
  for (int off = 32; off > 0; off >>= 1)
    local += __shfl_down(local, off, 64);
  __shared__ double s[16];
  const int lane = tid & 63;
  const int wv   = tid >> 6;
  if (lane == 0) s[wv] = local;
  __syncthreads();
  if (tid == 0) {
    double t = 0.0;
#pragma unroll
    for (int w = 0; w < 16; ++w) t += s[w];
    out[0] = (float)t;
  }
}

extern "C" void kernel_launch(void* const* d_in, const int* in_sizes, int n_in,
                              void* d_out, int out_size, void* d_ws, size_t ws_size,
                              hipStream_t stream) {
  const float* z_mu_n   = (const float*)d_in[0];
  const float* z_lv_n   = (const float*)d_in[1];
  const float* z_mu_e   = (const float*)d_in[2];
  const float* z_lv_e   = (const float*)d_in[3];
  const float* Alpha_mu = (const float*)d_in[4];
  const float* Beta_mu  = (const float*)d_in[5];
  const float* elog     = (const float*)d_in[6];
  const float* mu_A     = (const float*)d_in[7];
  const float* mu_B     = (const float*)d_in[8];
  const int*   eidx     = (const int*)d_in[9];

  const int D = in_sizes[4];
  const int N = in_sizes[0] / D;
  const int E = in_sizes[9] / 2;
  const long long N2 = (long long)N * N;
  const long long ND = (long long)N * D;

  double* partials = (double*)d_ws;
  float* out = (float*)d_out;

  const int spB = 4096, edB = 1024, klB = 128;
  const int nB = spB + edB + klB;

  k_main<<<nB, 256, 0, stream>>>(
      (const float4*)elog, N2 / 4,
      eidx, elog, N, E,
      (const float4*)z_mu_n, (const float4*)z_lv_n,
      (const float4*)z_mu_e, (const float4*)z_lv_e,
      (const float4*)mu_A, (const float4*)mu_B,
      ND / 4, D / 4 - 1,
      partials, spB, edB);
  k_final<<<1, 1024, 0, stream>>>(partials, nB, spB, edB,
                                  Alpha_mu, Beta_mu, mu_A, mu_B, out,
                                  D, 1.0 / (double)N2, 1.0 / (double)ND);
}